// Round 10
// baseline (387.752 us; speedup 1.0000x reference)
//
#include <hip/hip_runtime.h>
#include <hip/hip_bf16.h>
#include <stdint.h>

#define SQL 2048
#define EMB 1024
#define NHD 16
#define HDD 64

typedef __bf16 bf16x8 __attribute__((ext_vector_type(8)));
typedef __bf16 bf16x4 __attribute__((ext_vector_type(4)));
typedef float f32x4 __attribute__((ext_vector_type(4)));
typedef float f32x16 __attribute__((ext_vector_type(16)));

__device__ __forceinline__ f32x4 mfma16(bf16x8 a, bf16x8 b, f32x4 c) {
    return __builtin_amdgcn_mfma_f32_16x16x32_bf16(a, b, c, 0, 0, 0);
}
__device__ __forceinline__ f32x16 mfma32(bf16x8 a, bf16x8 b, f32x16 c) {
    return __builtin_amdgcn_mfma_f32_32x32x16_bf16(a, b, c, 0, 0, 0);
}

// async global->LDS, 16B per lane. lds must be wave-uniform base; HW adds lane*16.
__device__ __forceinline__ void gload_lds16(const __bf16* g, __bf16* lds) {
    __builtin_amdgcn_global_load_lds(
        (const __attribute__((address_space(1))) uint32_t*)g,
        (__attribute__((address_space(3))) uint32_t*)lds,
        16, 0, 0);
}

// ---------------- fused fp32 -> bf16 cast of all 5 tensors ----------------
__global__ void cast5_kernel(const float* __restrict__ x, const float* __restrict__ wq,
                             const float* __restrict__ wk, const float* __restrict__ wv,
                             const float* __restrict__ wo, __bf16* __restrict__ out)
{
    int i = blockIdx.x * blockDim.x + threadIdx.x;   // float4 units; 1536K total
    const float* src; int off;
    if      (i < (512 << 10))  { src = x;  off = 0; }
    else if (i < (768 << 10))  { src = wq; off = 512 << 10; }
    else if (i < (1024 << 10)) { src = wk; off = 768 << 10; }
    else if (i < (1280 << 10)) { src = wv; off = 1024 << 10; }
    else                       { src = wo; off = 1280 << 10; }
    float4 v = ((const float4*)src)[i - off];
    bf16x4 o;
    o[0] = (__bf16)v.x; o[1] = (__bf16)v.y; o[2] = (__bf16)v.z; o[3] = (__bf16)v.w;
    ((bf16x4*)out)[i] = o;
}

// ---------------- GEMM: C = (A @ B^T + bias) * scale ----------------
// R10: BM=64 x BN=128 tiles -> QKV grid 768 = EXACTLY 3 blocks/CU (LDS 48KB,
// launch_bounds(256,3)); out-proj grid 256 = 1/CU (was 128 = 0.5/CU, half GPU
// idle). Same BK=64 dbuf + 1 barrier/step + T2 swizzle + XCD-pinned decode.
// Accumulation k-order per output element unchanged -> bit-identical results.
// TRZ2: z==2 output written TRANSPOSED (Vt[e][s]).
template<bool OUT_BF16, bool TRZ2>
__global__ __launch_bounds__(256, 3)
void gemm_bt(const __bf16* __restrict__ A,
             const __bf16* __restrict__ B0, const __bf16* __restrict__ B1, const __bf16* __restrict__ B2,
             const float* __restrict__ bias0, const float* __restrict__ bias1, const float* __restrict__ bias2,
             void* __restrict__ out0, void* __restrict__ out1, void* __restrict__ out2,
             float s0, float s1, float s2,
             int M, int N, int K, int nmtiles)
{
    // flat decode: xcd=b&7; idx=b>>3; p=idx/nmtiles; bm_i=idx%nmtiles;
    // pid=xcd+8p -> bn panel = pid&7 (=xcd), z = pid>>3 (=p).
    const int b    = blockIdx.x;
    const int xcd  = b & 7;
    const int idx  = b >> 3;
    const int p    = idx / nmtiles;
    const int bm_i = idx - p * nmtiles;
    const int pid  = xcd + 8 * p;
    const int bn   = (pid & 7) * 128;
    const int bm   = bm_i * 64;
    const int z    = pid >> 3;

    const __bf16* B = B0; const float* bias = bias0; void* Cout = out0; float cscale = s0;
    if (z == 1) { B = B1; bias = bias1; Cout = out1; cscale = s1; }
    if (z == 2) { B = B2; bias = bias2; Cout = out2; cscale = s2; }

    // dbuf: As 64x64, Bs 128x64 (rows of 128B); data slot s at phys slot
    // s^(row&7) (16B units) -> conflict-free ds_read_b128.
    __shared__ __attribute__((aligned(16))) __bf16 As[2][64 * 64];
    __shared__ __attribute__((aligned(16))) __bf16 Bs[2][128 * 64];

    const int tid  = threadIdx.x;
    const int lane = tid & 63;
    const int wave = tid >> 6;
    const int lrow = lane & 15;
    const int quad = lane >> 4;
    const int wm = (wave >> 1) * 32;   // 2 m-halves of 32
    const int wn = (wave & 1) * 64;    // 2 n-halves of 64

    const f32x4 fzero = {0.f, 0.f, 0.f, 0.f};
    f32x4 acc[2][4];
#pragma unroll
    for (int i = 0; i < 2; i++)
#pragma unroll
        for (int j = 0; j < 4; j++) acc[i][j] = fzero;

    const int srow  = lane >> 3;                 // 0..7
    const int sslot = (lane & 7) ^ srow;         // pre-swizzled data slot

    auto stage = [&](int sbuf, int k0) {
#pragma unroll
        for (int j = 0; j < 2; j++) {            // A: 64 rows, 2 gloads/wave
            int r0 = wave * 16 + j * 8;
            gload_lds16(&A[(size_t)(bm + r0 + srow) * K + k0 + sslot * 8], &As[sbuf][r0 * 64]);
        }
#pragma unroll
        for (int j = 0; j < 4; j++) {            // B: 128 rows, 4 gloads/wave
            int r0 = wave * 32 + j * 8;
            gload_lds16(&B[(size_t)(bn + r0 + srow) * K + k0 + sslot * 8], &Bs[sbuf][r0 * 64]);
        }
    };

    const int nt = K >> 6;   // BK=64
    int buf = 0;
    stage(0, 0);
    __syncthreads();

    for (int t = 0; t < nt; t++) {
        if (t < nt - 1) stage(buf ^ 1, (t + 1) * 64);
        bf16x8 af[2][2], bfr[4][2];
#pragma unroll
        for (int i = 0; i < 2; i++) {
            int ra = wm + i * 16 + lrow;
#pragma unroll
            for (int ks = 0; ks < 2; ks++) {
                int sa = (((ks << 2) | quad) ^ (ra & 7)) << 3;
                af[i][ks] = *(const bf16x8*)&As[buf][ra * 64 + sa];
            }
        }
#pragma unroll
        for (int i = 0; i < 4; i++) {
            int rb = wn + i * 16 + lrow;
#pragma unroll
            for (int ks = 0; ks < 2; ks++) {
                int sb = (((ks << 2) | quad) ^ (rb & 7)) << 3;
                bfr[i][ks] = *(const bf16x8*)&Bs[buf][rb * 64 + sb];
            }
        }
#pragma unroll
        for (int ks = 0; ks < 2; ks++)
#pragma unroll
            for (int mi = 0; mi < 2; mi++)
#pragma unroll
                for (int ni = 0; ni < 4; ni++)
                    acc[mi][ni] = mfma16(af[mi][ks], bfr[ni][ks], acc[mi][ni]);
        __syncthreads();   // drains stage(t+1) vmcnt + hands buffers
        buf ^= 1;
    }

    const bool trz = TRZ2 && (z == 2);
#pragma unroll
    for (int mi = 0; mi < 2; mi++) {
        int row = bm + wm + mi * 16 + quad * 4;
#pragma unroll
        for (int ni = 0; ni < 4; ni++) {
            int col = bn + wn + ni * 16 + lrow;
            float bv = bias[col];
            if (trz) {
                bf16x4 t;
#pragma unroll
                for (int r = 0; r < 4; r++) t[r] = (__bf16)((acc[mi][ni][r] + bv) * cscale);
                *(bf16x4*)&((__bf16*)Cout)[(size_t)col * SQL + row] = t;
            } else {
#pragma unroll
                for (int r = 0; r < 4; r++) {
                    float v = (acc[mi][ni][r] + bv) * cscale;
                    if (OUT_BF16) ((__bf16*)Cout)[(size_t)(row + r) * N + col] = (__bf16)v;
                    else          ((float*)Cout)[(size_t)(row + r) * N + col] = v;
                }
            }
        }
    }
}

// ---------------- fused attention ---------------- (byte-identical to R9, passed)
__global__ __launch_bounds__(256, 2)
void attn_kernel(const __bf16* __restrict__ Qg, const __bf16* __restrict__ Kg,
                 const __bf16* __restrict__ Vt, float* __restrict__ attn,
                 __bf16* __restrict__ ctx)
{
    __shared__ __attribute__((aligned(16))) __bf16 Ks[2][64 * 64];
    __shared__ __attribute__((aligned(16))) __bf16 Vs[2][64 * 64];   // Vs[d][k]
    __shared__ __attribute__((aligned(16))) float  Pf[2][64 * 68];   // f32 P tile, dbuf
    __shared__ float Lb[4][64];                                       // per-wave partial l[q]
    float* Ored = &Pf[0][0];   // [d][q] stride 66; aliases Pf[0] (dead after last coop read)

    const int tid  = threadIdx.x;
    const int lane = tid & 63;
    const int w    = tid >> 6;
    const int wq   = w & 1;
    const int wk   = w >> 1;
    const int l31  = lane & 31;
    const int hi   = lane >> 5;

    // XCD-pinned decode: b%8 = XCD; head h = xcd + 8*(slot>>5); qtile = slot&31.
    const int b    = blockIdx.x;
    const int xcd  = b & 7;
    const int slot = b >> 3;                 // 0..63
    const int h    = xcd + ((slot >> 5) << 3);
    const int q0   = (slot & 31) * 64;

    const f32x16 Z16 = {0.f,0.f,0.f,0.f,0.f,0.f,0.f,0.f,0.f,0.f,0.f,0.f,0.f,0.f,0.f,0.f};

    // Q B-fragments for BOTH q-halves (pass 1 needs q=64); Q pre-scaled 1/32
    bf16x8 qf[2][4];
#pragma unroll
    for (int qg = 0; qg < 2; qg++) {
        const __bf16* qp = &Qg[(size_t)(q0 + qg * 32 + l31) * EMB + h * HDD + hi * 8];
#pragma unroll
        for (int ds = 0; ds < 4; ds++) qf[qg][ds] = *(const bf16x8*)&qp[ds * 16];
    }

    // ---- pass 1: l = sum exp(S); LDS-free, barrier-free, prefetch-pipelined ----
    {
        const __bf16* kp = &Kg[(size_t)(w * 32 + l31) * EMB + h * HDD + hi * 8];
        const size_t tstep = (size_t)128 * EMB;
        bf16x8 kcur[4], knxt[4];
#pragma unroll
        for (int ds = 0; ds < 4; ds++) kcur[ds] = *(const bf16x8*)&kp[ds * 16];
        float ls0 = 0.f, ls1 = 0.f;
        for (int t = 0; t < 16; t++) {
            if (t < 15) {
#pragma unroll
                for (int ds = 0; ds < 4; ds++)
                    knxt[ds] = *(const bf16x8*)&kp[(size_t)(t + 1) * tstep + ds * 16];
            }
            f32x16 sA = Z16, sB = Z16;
            __builtin_amdgcn_s_setprio(1);
#pragma unroll
            for (int ds = 0; ds < 4; ds++) {
                sA = mfma32(kcur[ds], qf[0][ds], sA);
                sB = mfma32(kcur[ds], qf[1][ds], sB);
            }
            __builtin_amdgcn_s_setprio(0);
#pragma unroll
            for (int r = 0; r < 16; r++) { ls0 += __expf(sA[r]); ls1 += __expf(sB[r]); }
            if (t < 15) {
#pragma unroll
                for (int ds = 0; ds < 4; ds++) kcur[ds] = knxt[ds];
            }
        }
        ls0 += __shfl_xor(ls0, 32);
        ls1 += __shfl_xor(ls1, 32);
        if (hi == 0) { Lb[w][l31] = ls0; Lb[w][32 + l31] = ls1; }
    }

    // pass-2 staging helpers: 8 rows x 128B per gload; phys slot = (lane&7)^(row&7)
    const int srow  = lane >> 3;
    const int sslot = (lane & 7) ^ (srow & 7);
    auto stageK = [&](int buf, int k0) {
#pragma unroll
        for (int j = 0; j < 2; j++) {
            int r = w * 16 + j * 8;
            gload_lds16(&Kg[(size_t)(k0 + r + srow) * EMB + h * HDD + sslot * 8],
                        &Ks[buf][r * 64]);
        }
    };
    auto stageV = [&](int buf, int k0) {
#pragma unroll
        for (int j = 0; j < 2; j++) {
            int r = w * 16 + j * 8;
            gload_lds16(&Vt[(size_t)(h * HDD + r + srow) * SQL + k0 + sslot * 8],
                        &Vs[buf][r * 64]);
        }
    };

    // overlap pass-2 tile-0 staging with the Lb merge barrier
    stageK(0, 0);
    stageV(0, 0);
    __syncthreads();

    float rinv;
    {
        int q = wq * 32 + l31;
        rinv = 1.f / (Lb[0][q] + Lb[1][q] + Lb[2][q] + Lb[3][q]);
    }

    f32x16 o0 = Z16, o1 = Z16;
    float* __restrict__ attn_h = attn + (size_t)h * SQL * SQL;
    const int krowoff = (wk * 32 + l31) * 64;
    const int lane7   = lane & 7;
    const int vrow0 = l31 * 64;
    const int vrow1 = (32 + l31) * 64;
    const int pq    = (wq * 32 + l31) * 68;   // lane's Pf row base
    const bf16x8* qfp = qf[wq];

    // ---- pass 2: recompute S -> Pf (f32, LDS) -> PV; coalesced coop store; 1 barrier/tile ----
    int buf = 0;
    for (int t = 0; t < 32; t++) {
        const int k0 = t * 64;
        if (t < 31) { stageK(buf ^ 1, k0 + 64); stageV(buf ^ 1, k0 + 64); }
        f32x16 s = Z16;
#pragma unroll
        for (int ds = 0; ds < 4; ds++) {
            bf16x8 kf = *(const bf16x8*)&Ks[buf][krowoff + ((((ds << 1) | hi) ^ lane7) << 3)];
            s = mfma32(kf, qfp[ds], s);
        }
        // P = exp(S)*rinv -> Pf quadrant (f32x4 LDS writes)
#pragma unroll
        for (int g = 0; g < 4; g++) {
            f32x4 pv;
#pragma unroll
            for (int i = 0; i < 4; i++) pv[i] = __expf(s[g * 4 + i]) * rinv;
            *(f32x4*)&Pf[buf][pq + wk * 32 + g * 8 + hi * 4] = pv;
        }
        // PV from own Pf quadrant (wave-local, in-order ds) with f32->bf16 cvt
#pragma unroll
        for (int kt = 0; kt < 2; kt++) {
            const float* pp = &Pf[buf][pq + wk * 32 + kt * 16 + hi * 8];
            f32x4 pA = *(const f32x4*)pp;
            f32x4 pB = *(const f32x4*)(pp + 4);
            bf16x8 pf;
#pragma unroll
            for (int i = 0; i < 4; i++) { pf[i] = (__bf16)pA[i]; pf[i + 4] = (__bf16)pB[i]; }
            int vslot = (((wk << 2) | (kt << 1) | hi) ^ lane7) << 3;
            bf16x8 v0 = *(const bf16x8*)&Vs[buf][vrow0 + vslot];
            bf16x8 v1 = *(const bf16x8*)&Vs[buf][vrow1 + vslot];
            o0 = mfma32(v0, pf, o0);
            o1 = mfma32(v1, pf, o1);
        }
        __syncthreads();   // Pf[buf] complete block-wide; staging(t+1) landed
        // cooperative COALESCED attn store: 16 lanes x 16B = 256B contiguous per row
#pragma unroll
        for (int j = 0; j < 4; j++) {
            int lin = j * 256 + tid;
            int r   = lin >> 4;             // 0..63
            int c   = (lin & 15) << 2;      // 0..60 step 4
            f32x4 v = *(const f32x4*)&Pf[buf][r * 68 + c];
            *(f32x4*)&attn_h[(size_t)(q0 + r) * SQL + k0 + c] = v;
        }
        buf ^= 1;
    }

    // ---- sum partial O across the wk pair, write ctx ----
    if (wk == 1) {
#pragma unroll
        for (int g = 0; g < 4; g++)
#pragma unroll
            for (int i = 0; i < 4; i++) {
                int dl = i + g * 8 + hi * 4;
                Ored[dl * 66 + wq * 32 + l31]        = o0[g * 4 + i];
                Ored[(32 + dl) * 66 + wq * 32 + l31] = o1[g * 4 + i];
            }
    }
    __syncthreads();
    if (wk == 0) {
        __bf16* crow = &ctx[(size_t)(q0 + wq * 32 + l31) * EMB + h * HDD];
#pragma unroll
        for (int g = 0; g < 4; g++) {
            bf16x4 c0, c1;
#pragma unroll
            for (int i = 0; i < 4; i++) {
                int dl = i + g * 8 + hi * 4;
                c0[i] = (__bf16)(o0[g * 4 + i] + Ored[dl * 66 + wq * 32 + l31]);
                c1[i] = (__bf16)(o1[g * 4 + i] + Ored[(32 + dl) * 66 + wq * 32 + l31]);
            }
            *(bf16x4*)&crow[g * 8 + hi * 4]      = c0;
            *(bf16x4*)&crow[32 + g * 8 + hi * 4] = c1;
        }
    }
}

// ---------------- launch ----------------
extern "C" void kernel_launch(void* const* d_in, const int* in_sizes, int n_in,
                              void* d_out, int out_size, void* d_ws, size_t ws_size,
                              hipStream_t stream)
{
    const float* x  = (const float*)d_in[0];
    const float* Wq = (const float*)d_in[1];
    const float* bq = (const float*)d_in[2];
    const float* Wk = (const float*)d_in[3];
    const float* bk = (const float*)d_in[4];
    const float* Wv = (const float*)d_in[5];
    const float* bv = (const float*)d_in[6];
    const float* Wo = (const float*)d_in[7];
    const float* bo = (const float*)d_in[8];

    float* out  = (float*)d_out;
    float* attn = out + (size_t)SQL * EMB;

    const size_t M1 = 1u << 20;
    __bf16* wsb = (__bf16*)d_ws;
    __bf16* xb  = wsb;            // 2M
    __bf16* wqb = wsb + 2 * M1;   // 1M
    __bf16* wkb = wsb + 3 * M1;   // 1M
    __bf16* wvb = wsb + 4 * M1;   // 1M
    __bf16* wob = wsb + 5 * M1;   // 1M
    __bf16* Qb  = wsb + 6 * M1;   // 2M
    __bf16* Kb  = wsb + 8 * M1;   // 2M
    __bf16* Vtb = wsb + 12 * M1;  // 2M (V written transposed by QKV GEMM)
    __bf16* ctb = wsb + 14 * M1;  // 2M

    cast5_kernel<<<6144, 256, 0, stream>>>(x, Wq, Wk, Wv, Wo, wsb);

    // Q,K,V = x @ W^T + b   (Q scaled by 1/32; V written transposed -> Vtb)
    // BM=64: 32 mtiles x 8 ntiles x 3 = 768 blocks = exactly 3/CU
    gemm_bt<true, true><<<768, 256, 0, stream>>>(
        xb, wqb, wkb, wvb, bq, bk, bv,
        (void*)Qb, (void*)Kb, (void*)Vtb,
        0.03125f, 1.0f, 1.0f, SQL, EMB, EMB, 32);

    // flat 512-block grid, XCD-pinned head decode inside the kernel
    attn_kernel<<<512, 256, 0, stream>>>(Qb, Kb, Vtb, attn, ctb);

    // out = ctx @ Wo^T + bo  (fp32 output), 32x8 = 256 blocks = 1/CU
    gemm_bt<false, false><<<256, 256, 0, stream>>>(
        ctb, wob, wob, wob, bo, bo, bo,
        (void*)out, (void*)out, (void*)out,
        1.0f, 1.0f, 1.0f, SQL, EMB, EMB, 32);
}